// Round 5
// baseline (275.257 us; speedup 1.0000x reference)
//
#include <hip/hip_runtime.h>
#include <hip/hip_bf16.h>

typedef __attribute__((ext_vector_type(4))) float f32x4;
typedef __attribute__((ext_vector_type(16))) float f32x16;
typedef __attribute__((ext_vector_type(8))) short bf16x8;
typedef __attribute__((ext_vector_type(4))) unsigned short u16x4;
typedef __attribute__((ext_vector_type(8))) unsigned short u16x8;
typedef __attribute__((ext_vector_type(2))) unsigned int u32x2;

#define MFMA16(a, b, c) __builtin_amdgcn_mfma_f32_16x16x32_bf16((a), (b), (c), 0, 0, 0)
#define MFMA32(a, b, c) __builtin_amdgcn_mfma_f32_32x32x16_bf16((a), (b), (c), 0, 0, 0)

static __device__ __forceinline__ unsigned short f2bf(float f) {
    union { float f; unsigned int u; } v; v.f = f;
    unsigned int r = v.u + 0x7FFFu + ((v.u >> 16) & 1u);  // RNE
    return (unsigned short)(r >> 16);
}
// HW packed f32->bf16 (T12 recipe; src0 -> low half)
static __device__ __forceinline__ unsigned int pk2(float x, float y) {
    unsigned int r;
    asm("v_cvt_pk_bf16_f32 %0, %1, %2" : "=v"(r) : "v"(x), "v"(y));
    return r;
}

static __device__ __forceinline__ void gload_lds16(const void* g, void* l) {
    __builtin_amdgcn_global_load_lds(
        (const __attribute__((address_space(1))) void*)g,
        (__attribute__((address_space(3))) void*)l, 16, 0, 0);
}

// ---------------------------------------------------------------------------
// convert_act: fp32 -> bf16, 8 elems/thread.
// ---------------------------------------------------------------------------
__global__ __launch_bounds__(256) void convert_act(
    const float* __restrict__ q, const float* __restrict__ k,
    const float* __restrict__ v, unsigned short* __restrict__ qc,
    unsigned short* __restrict__ kc, unsigned short* __restrict__ vc) {
    const float* src = blockIdx.y == 0 ? q : (blockIdx.y == 1 ? k : v);
    unsigned short* dst = blockIdx.y == 0 ? qc : (blockIdx.y == 1 ? kc : vc);
    size_t off = ((size_t)blockIdx.x * 256 + threadIdx.x) * 8;
    f32x4 a = *(const f32x4*)&src[off];
    f32x4 b = *(const f32x4*)&src[off + 4];
    union { unsigned int u[4]; u16x8 v; } o;
    o.u[0] = pk2(a[0], a[1]); o.u[1] = pk2(a[2], a[3]);
    o.u[2] = pk2(b[0], b[1]); o.u[3] = pk2(b[2], b[3]);
    *(u16x8*)&dst[off] = o.v;
}

// ---------------------------------------------------------------------------
// transpose_w: W[k][n] fp32 -> Wt[n][k] bf16. 64x64 tiles, z = matrix 0..3.
// ---------------------------------------------------------------------------
__global__ __launch_bounds__(256) void transpose_w(
    const float* __restrict__ Wq, const float* __restrict__ Wk,
    const float* __restrict__ Wv, const float* __restrict__ Wo,
    unsigned short* __restrict__ Wt_all, unsigned short* __restrict__ Wot) {
    __shared__ unsigned short T[64][65];
    const int z = blockIdx.z;
    const float* W = z == 0 ? Wq : (z == 1 ? Wk : (z == 2 ? Wv : Wo));
    unsigned short* Wt = z < 3 ? (Wt_all + (size_t)z * 1024 * 1024) : Wot;
    const int k0 = blockIdx.y * 64, n0 = blockIdx.x * 64;
    const int t = threadIdx.x;
    const int rl = t >> 4, c4 = (t & 15) * 4;
#pragma unroll
    for (int i = 0; i < 4; ++i) {
        f32x4 v = *(const f32x4*)&W[(size_t)(k0 + rl + 16 * i) * 1024 + n0 + c4];
#pragma unroll
        for (int j = 0; j < 4; ++j) T[rl + 16 * i][c4 + j] = f2bf(v[j]);
    }
    __syncthreads();
#pragma unroll
    for (int i = 0; i < 4; ++i) {
        u16x4 o;
#pragma unroll
        for (int j = 0; j < 4; ++j) o[j] = T[c4 + j][rl + 16 * i];
        *(u16x4*)&Wt[(size_t)(n0 + rl + 16 * i) * 1024 + k0 + c4] = o;
    }
}

// ---------------------------------------------------------------------------
// gemm_fast: 2-phase double-buffered (T3-minimum): prefetch tile k+1 into
// buf^1 via global_load_lds BEFORE computing buf; ONE barrier per K-step.
// 128xBN tile, 4 waves, BK=32.
// ---------------------------------------------------------------------------
template <bool OUT_BF16, int BN>
__global__ __launch_bounds__(256, 2) void gemm_fast(
    const unsigned short* __restrict__ A0, const unsigned short* __restrict__ A1,
    const unsigned short* __restrict__ A2, const unsigned short* __restrict__ Wt,
    const float* __restrict__ b0, const float* __restrict__ b1,
    const float* __restrict__ b2, void* __restrict__ Outv, int ldo) {
    constexpr int NF = BN / 32;  // n-frags per wave
    __shared__ __align__(16) unsigned short As[2][128 * 32];
    __shared__ __align__(16) unsigned short Bs[2][BN * 32];

    const int t = threadIdx.x;
    const int w = t >> 6, lane = t & 63;
    const int wr = w >> 1, wc = w & 1;
    const int g = lane >> 4, r15 = lane & 15;
    const int bm = blockIdx.y * 128;
    const int bn = blockIdx.x * BN;
    const int msel = bn >> 10;
    const unsigned short* A = msel == 0 ? A0 : (msel == 1 ? A1 : A2);
    const float* bias = msel == 0 ? b0 : (msel == 1 ? b1 : b2);
    const int l4 = lane >> 2, c8 = (lane & 3) * 8;

    f32x4 acc[4][NF];
#pragma unroll
    for (int m = 0; m < 4; ++m)
#pragma unroll
        for (int n = 0; n < NF; ++n) acc[m][n] = (f32x4){0.f, 0.f, 0.f, 0.f};

#define G_STAGE(BUF, KT)                                                          \
    {                                                                             \
        gload_lds16(&A[(size_t)(bm + 16 * w + l4) * 1024 + (KT) + c8],            \
                    &As[BUF][w * 512]);                                           \
        gload_lds16(&A[(size_t)(bm + 16 * (w + 4) + l4) * 1024 + (KT) + c8],      \
                    &As[BUF][(w + 4) * 512]);                                     \
        if (BN == 128) {                                                          \
            gload_lds16(&Wt[(size_t)(bn + 16 * w + l4) * 1024 + (KT) + c8],       \
                        &Bs[BUF][(w * 512) % (BN * 32)]);                         \
            gload_lds16(&Wt[(size_t)(bn + 16 * (w + 4) + l4) * 1024 + (KT) + c8], \
                        &Bs[BUF][((w + 4) * 512) % (BN * 32)]);                   \
        } else if (w < 4) {                                                       \
            gload_lds16(&Wt[(size_t)(bn + 16 * w + l4) * 1024 + (KT) + c8],       \
                        &Bs[BUF][(w * 512) % (BN * 32)]);                         \
        }                                                                         \
    }

    G_STAGE(0, 0);
    __syncthreads();

    int cur = 0;
    for (int kt = 0; kt < 1024; kt += 32) {
        if (kt < 992) G_STAGE(cur ^ 1, kt + 32);
        bf16x8 af[4], bfr[NF];
#pragma unroll
        for (int m = 0; m < 4; ++m)
            af[m] = *(const bf16x8*)&As[cur][(wr * 64 + m * 16 + r15) * 32 + g * 8];
#pragma unroll
        for (int n = 0; n < NF; ++n)
            bfr[n] = *(const bf16x8*)&Bs[cur][(wc * (BN / 2) + n * 16 + r15) * 32 + g * 8];
        __builtin_amdgcn_s_setprio(1);
#pragma unroll
        for (int m = 0; m < 4; ++m)
#pragma unroll
            for (int n = 0; n < NF; ++n)
                acc[m][n] = MFMA16(af[m], bfr[n], acc[m][n]);
        __builtin_amdgcn_s_setprio(0);
        __syncthreads();
        cur ^= 1;
    }
#undef G_STAGE

    float* Of = (float*)Outv;
    unsigned short* Ob = (unsigned short*)Outv;
#pragma unroll
    for (int n = 0; n < NF; ++n) {
        int col = bn + wc * (BN / 2) + n * 16 + r15;
        float bv = bias[col & 1023];
#pragma unroll
        for (int m = 0; m < 4; ++m) {
#pragma unroll
            for (int r = 0; r < 4; ++r) {
                int row = bm + wr * 64 + m * 16 + g * 4 + r;
                float val = acc[m][n][r] + bv;
                if (OUT_BF16)
                    Ob[(size_t)row * ldo + col] = f2bf(val);
                else
                    Of[(size_t)row * ldo + col] = val;
            }
        }
    }
}

// ---------------------------------------------------------------------------
// Legacy fp32-A GEMM (fallback if ws too small).
// ---------------------------------------------------------------------------
template <bool A_BF16, bool OUT_BF16>
__global__ __launch_bounds__(256, 2) void gemm_kernel(
    const void* __restrict__ Av, const float* __restrict__ W,
    const float* __restrict__ bias, void* __restrict__ Outv) {
    __shared__ __align__(16) unsigned short As[128][40];
    __shared__ __align__(16) unsigned short Bs[128][40];

    const int t = threadIdx.x;
    const int bm = blockIdx.y * 128;
    const int bn = blockIdx.x * 128;
    const int w = t >> 6, lane = t & 63;
    const int wr = w >> 1, wc = w & 1;
    const int g = lane >> 4, r15 = lane & 15;

    f32x4 acc[4][4];
#pragma unroll
    for (int m = 0; m < 4; ++m)
#pragma unroll
        for (int n = 0; n < 4; ++n) acc[m][n] = (f32x4){0.f, 0.f, 0.f, 0.f};

    const float* Af = (const float*)Av;
    const unsigned short* Ab = (const unsigned short*)Av;

    for (int kt = 0; kt < 1024; kt += 32) {
        __syncthreads();
#pragma unroll
        for (int i = 0; i < 4; ++i) {
            int row = (t >> 3) + i * 32;
            int c4 = (t & 7) * 4;
            if (A_BF16) {
                u16x4 v = *(const u16x4*)&Ab[(size_t)(bm + row) * 1024 + kt + c4];
                *(u16x4*)&As[row][c4] = v;
            } else {
                f32x4 v = *(const f32x4*)&Af[(size_t)(bm + row) * 1024 + kt + c4];
                u16x4 o;
                o[0] = f2bf(v[0]); o[1] = f2bf(v[1]);
                o[2] = f2bf(v[2]); o[3] = f2bf(v[3]);
                *(u16x4*)&As[row][c4] = o;
            }
        }
#pragma unroll
        for (int i = 0; i < 4; ++i) {
            int k = (t >> 5) + i * 8;
            int c4 = (t & 31) * 4;
            f32x4 v = *(const f32x4*)&W[(size_t)(kt + k) * 1024 + bn + c4];
#pragma unroll
            for (int j = 0; j < 4; ++j) Bs[c4 + j][k] = f2bf(v[j]);
        }
        __syncthreads();
        bf16x8 af[4], bfr[4];
#pragma unroll
        for (int m = 0; m < 4; ++m)
            af[m] = *(const bf16x8*)&As[wr * 64 + m * 16 + r15][g * 8];
#pragma unroll
        for (int n = 0; n < 4; ++n)
            bfr[n] = *(const bf16x8*)&Bs[wc * 64 + n * 16 + r15][g * 8];
#pragma unroll
        for (int m = 0; m < 4; ++m)
#pragma unroll
            for (int n = 0; n < 4; ++n)
                acc[m][n] = MFMA16(af[m], bfr[n], acc[m][n]);
    }

    float* Of = (float*)Outv;
    unsigned short* Ob = (unsigned short*)Outv;
#pragma unroll
    for (int n = 0; n < 4; ++n) {
        int col = bn + wc * 64 + n * 16 + r15;
        float bv = bias[col];
#pragma unroll
        for (int m = 0; m < 4; ++m) {
#pragma unroll
            for (int r = 0; r < 4; ++r) {
                int row = bm + wr * 64 + m * 16 + g * 4 + r;
                float val = acc[m][n][r] + bv;
                if (OUT_BF16)
                    Ob[(size_t)row * 1024 + col] = f2bf(val);
                else
                    Of[(size_t)row * 1024 + col] = val;
            }
        }
    }
}

// ---------------------------------------------------------------------------
// attn32: swapped-operand 32x32 flash attention, KV-SPLIT version.
// Per block: 64 q-rows, 4 waves = (wq = q-half) x (wp = KV parity).
// Waves wp=0 consume even 64-key tiles (buf0), wp=1 odd tiles (buf1) —
// both LDS buffers are live simultaneously; partials merged by LSE at end.
// Grid 1024 (4 blocks/CU). K/V^T LDS stride 160B, XOR swizzle (row&7)<<4.
// ---------------------------------------------------------------------------
__global__ __launch_bounds__(256, 4) void attn32_kernel(
    const unsigned short* __restrict__ Q, const unsigned short* __restrict__ K,
    const unsigned short* __restrict__ V, unsigned short* __restrict__ O, int ld) {
    __shared__ __align__(16) unsigned short Kls[2][64 * 80];
    __shared__ __align__(16) unsigned short Vls[2][64 * 80];

    const int t = threadIdx.x;
    const int w = t >> 6, lane = t & 63;
    const int q5 = lane & 31, hi = lane >> 5;
    const int wq = w & 1, wp = w >> 1;

    // XCD swizzle (1024 blocks, 1024%8==0 -> bijective)
    const int id = blockIdx.x;
    const int sid = (id & 7) * 128 + (id >> 3);
    const int bh = sid >> 4, qb = sid & 15;
    const int b = bh >> 4, h = bh & 15;
    const int brow = b * 1024;
    const int q0 = qb * 64;

    const float c2 = 0.18033688f;  // (1/8) * log2(e)

    const unsigned short* Qrow = Q + (size_t)(brow + q0 + wq * 32 + q5) * ld + h * 64;
    bf16x8 qreg[8];
#pragma unroll
    for (int j = 0; j < 8; ++j) qreg[j] = *(const bf16x8*)&Qrow[8 * j];
    bf16x8 qsel[4];
#pragma unroll
    for (int kk = 0; kk < 4; ++kk) qsel[kk] = hi ? qreg[2 * kk + 1] : qreg[2 * kk];

    // staging roles: K by (row, 16B slot); V by (key-pair, d-chunk of 8)
    const int krow = t >> 2, kpart = t & 3;
    const int vp = t & 31, vdc = t >> 5;  // keys 2vp,2vp+1; d chunk 8*vdc
    const unsigned short* Kg = K + h * 64;
    const unsigned short* Vg = V + h * 64;

    u16x8 krA0, krA1, krB0, krB1, vrA0, vrA1, vrB0, vrB1;
    // load tiles T (keys T..T+63) and T+64
#define STG_LOAD2(T)                                                            \
    {                                                                           \
        size_t kroA = (size_t)(brow + (T) + krow) * ld;                         \
        krA0 = *(const u16x8*)&Kg[kroA + kpart * 8];                            \
        krA1 = *(const u16x8*)&Kg[kroA + kpart * 8 + 32];                       \
        size_t kroB = (size_t)(brow + (T) + 64 + krow) * ld;                    \
        krB0 = *(const u16x8*)&Kg[kroB + kpart * 8];                            \
        krB1 = *(const u16x8*)&Kg[kroB + kpart * 8 + 32];                       \
        size_t vroA = (size_t)(brow + (T) + 2 * vp) * ld;                       \
        vrA0 = *(const u16x8*)&Vg[vroA + vdc * 8];                              \
        vrA1 = *(const u16x8*)&Vg[vroA + ld + vdc * 8];                         \
        size_t vroB = (size_t)(brow + (T) + 64 + 2 * vp) * ld;                  \
        vrB0 = *(const u16x8*)&Vg[vroB + vdc * 8];                              \
        vrB1 = *(const u16x8*)&Vg[vroB + ld + vdc * 8];                         \
    }
#define STG_W1(BUF, KR0, KR1, VR0, VR1)                                         \
    {                                                                           \
        char* kb_ = (char*)Kls[BUF];                                            \
        int tg_ = (krow & 7) << 4;                                              \
        *(u16x8*)(kb_ + krow * 160 + ((kpart * 16) ^ tg_)) = KR0;               \
        *(u16x8*)(kb_ + krow * 160 + (((kpart + 4) * 16) ^ tg_)) = KR1;         \
        char* vb_ = (char*)Vls[BUF];                                            \
        _Pragma("unroll") for (int j_ = 0; j_ < 8; ++j_) {                      \
            int d_ = vdc * 8 + j_;                                              \
            unsigned int pk_ = (unsigned int)(unsigned short)VR0[j_] |          \
                               ((unsigned int)(unsigned short)VR1[j_] << 16);   \
            *(unsigned int*)(vb_ + d_ * 160 + ((vp * 4) ^ ((d_ & 7) << 4)))     \
                = pk_;                                                          \
        }                                                                       \
    }
#define STG_WRITE2()                          \
    {                                         \
        STG_W1(0, krA0, krA1, vrA0, vrA1);    \
        STG_W1(1, krB0, krB1, vrB0, vrB1);    \
    }

    f32x16 acc0 = {}, acc1 = {};
    float mrun = -1e30f, lrun = 0.f;

    STG_LOAD2(0);
    STG_WRITE2();
    __syncthreads();

    for (int it = 0; it < 8; ++it) {
        const bool more = it < 7;
        if (more) STG_LOAD2(it * 128 + 128);

        // ---- QK^T from buf[wp]
        char* kb = (char*)Kls[wp];
        f32x16 st0 = {}, st1 = {};
        {
            const int tg0 = (q5 & 7) << 4;
            char* kp0 = kb + q5 * 160;
            char* kp1 = kb + (q5 + 32) * 160;
            __builtin_amdgcn_s_setprio(1);
#pragma unroll
            for (int kk = 0; kk < 4; ++kk) {
                int so = ((2 * kk + hi) * 16) ^ tg0;
                bf16x8 kf0 = *(const bf16x8*)(kp0 + so);
                bf16x8 kf1 = *(const bf16x8*)(kp1 + so);
                st0 = MFMA32(kf0, qsel[kk], st0);
                st1 = MFMA32(kf1, qsel[kk], st1);
            }
            __builtin_amdgcn_s_setprio(0);
        }

        // ---- online softmax with defer-max (T13)
        float mloc = fmaxf(st0[0], st0[1]);
#pragma unroll
        for (int r = 2; r < 16; ++r) mloc = fmaxf(mloc, st0[r]);
#pragma unroll
        for (int r = 0; r < 16; ++r) mloc = fmaxf(mloc, st1[r]);
        mloc = fmaxf(mloc, __shfl_xor(mloc, 32));
        if (!__all(mloc - mrun <= 64.f)) {
            float mnew = fmaxf(mrun, mloc);
            float sf = exp2f((mrun - mnew) * c2);
            mrun = mnew;
            lrun *= sf;
#pragma unroll
            for (int r = 0; r < 16; ++r) { acc0[r] *= sf; acc1[r] *= sf; }
        }
        float mneg = -mrun * c2;
        float rs = 0.f;
#pragma unroll
        for (int r = 0; r < 16; ++r) {
            st0[r] = exp2f(fmaf(st0[r], c2, mneg));
            rs += st0[r];
        }
#pragma unroll
        for (int r = 0; r < 16; ++r) {
            st1[r] = exp2f(fmaf(st1[r], c2, mneg));
            rs += st1[r];
        }
        rs += __shfl_xor(rs, 32);
        lrun += rs;

        // ---- P^T pack (cvt_pk) + PV (O^T += V^T * P^T) from buf[wp]
        char* vb = (char*)Vls[wp];
        const int tgv = (q5 & 7) << 4;
        char* vp0 = vb + q5 * 160;
        char* vp1 = vb + (q5 + 32) * 160;
        __builtin_amdgcn_s_setprio(1);
#define PV_HALF(ST, CT)                                                         \
    _Pragma("unroll") for (int ks = 0; ks < 2; ++ks) {                          \
        unsigned int a0 = pk2(ST[8 * ks + 0], ST[8 * ks + 1]);                  \
        unsigned int a1 = pk2(ST[8 * ks + 2], ST[8 * ks + 3]);                  \
        unsigned int a2 = pk2(ST[8 * ks + 4], ST[8 * ks + 5]);                  \
        unsigned int a3 = pk2(ST[8 * ks + 6], ST[8 * ks + 7]);                  \
        unsigned int x0 = __shfl_xor(a0, 32), x1 = __shfl_xor(a1, 32);          \
        unsigned int x2 = __shfl_xor(a2, 32), x3 = __shfl_xor(a3, 32);          \
        union { unsigned int u[4]; bf16x8 v; } pfu;                             \
        pfu.u[0] = hi ? x2 : a0;                                                \
        pfu.u[1] = hi ? x3 : a1;                                                \
        pfu.u[2] = hi ? a2 : x0;                                                \
        pfu.u[3] = hi ? a3 : x1;                                                \
        int co = ((32 * (2 * (CT) + ks) + 16 * hi)) ^ tgv;                      \
        bf16x8 vf0 = *(const bf16x8*)(vp0 + co);                                \
        bf16x8 vf1 = *(const bf16x8*)(vp1 + co);                                \
        acc0 = MFMA32(vf0, pfu.v, acc0);                                        \
        acc1 = MFMA32(vf1, pfu.v, acc1);                                        \
    }
        PV_HALF(st0, 0);
        PV_HALF(st1, 1);
        __builtin_amdgcn_s_setprio(0);

        if (more) {
            __syncthreads();       // all waves done reading both bufs
            STG_WRITE2();
            __syncthreads();       // bufs refreshed for next iter
        }
    }

    // ---- LSE-merge of wp=0 / wp=1 partials, then store
    float* MG = (float*)Kls;  // 128 slots x 35 f32 = 17920 B <= 20480 B
    const int slot = (wq * 64 + lane) * 35;
    __syncthreads();  // everyone done with Kls as tile storage
    if (wp == 1) {
        MG[slot] = mrun;
        MG[slot + 1] = lrun;
#pragma unroll
        for (int r = 0; r < 16; ++r) {
            MG[slot + 2 + r] = acc0[r];
            MG[slot + 18 + r] = acc1[r];
        }
    }
    __syncthreads();
    if (wp == 0) {
        float m1 = MG[slot], l1 = MG[slot + 1];
        float mn = fmaxf(mrun, m1);
        float fa = exp2f((mrun - mn) * c2);
        float fb = exp2f((m1 - mn) * c2);
        float inv = 1.0f / (lrun * fa + l1 * fb);
        fa *= inv; fb *= inv;
        unsigned short* Orow =
            O + (size_t)(brow + q0 + wq * 32 + q5) * 1024 + h * 64;
#pragma unroll
        for (int k = 0; k < 4; ++k) {
            int d0 = 8 * k + 4 * hi;
            u32x2 pa, pb;
            pa[0] = pk2(acc0[4 * k + 0] * fa + MG[slot + 2 + 4 * k + 0] * fb,
                        acc0[4 * k + 1] * fa + MG[slot + 2 + 4 * k + 1] * fb);
            pa[1] = pk2(acc0[4 * k + 2] * fa + MG[slot + 2 + 4 * k + 2] * fb,
                        acc0[4 * k + 3] * fa + MG[slot + 2 + 4 * k + 3] * fb);
            *(u32x2*)&Orow[d0] = pa;
            pb[0] = pk2(acc1[4 * k + 0] * fa + MG[slot + 18 + 4 * k + 0] * fb,
                        acc1[4 * k + 1] * fa + MG[slot + 18 + 4 * k + 1] * fb);
            pb[1] = pk2(acc1[4 * k + 2] * fa + MG[slot + 18 + 4 * k + 2] * fb,
                        acc1[4 * k + 3] * fa + MG[slot + 18 + 4 * k + 3] * fb);
            *(u32x2*)&Orow[32 + d0] = pb;
        }
    }
#undef STG_LOAD2
#undef STG_W1
#undef STG_WRITE2
#undef PV_HALF
}

extern "C" void kernel_launch(void* const* d_in, const int* in_sizes, int n_in,
                              void* d_out, int out_size, void* d_ws, size_t ws_size,
                              hipStream_t stream) {
    const float* q  = (const float*)d_in[0];
    const float* k  = (const float*)d_in[1];
    const float* v  = (const float*)d_in[2];
    const float* Wq = (const float*)d_in[3];
    const float* bq = (const float*)d_in[4];
    const float* Wk = (const float*)d_in[5];
    const float* bk = (const float*)d_in[6];
    const float* Wv = (const float*)d_in[7];
    const float* bv = (const float*)d_in[8];
    const float* Wo = (const float*)d_in[9];
    const float* bo = (const float*)d_in[10];

    const size_t M1 = (size_t)1024 * 1024;
    const size_t NEED = 28 * M1 * sizeof(unsigned short);  // 56 MB

    dim3 bt(256, 1, 1);
    if (ws_size >= NEED) {
        unsigned short* qc  = (unsigned short*)d_ws;       // 4M elems
        unsigned short* kc  = qc + 4 * M1;
        unsigned short* vc  = kc + 4 * M1;
        unsigned short* Wt  = vc + 4 * M1;                 // 3M elems
        unsigned short* Wot = Wt + 3 * M1;                 // 1M elems
        unsigned short* QKV = Wot + M1;                    // 12M elems [4096][3072]
        unsigned short* Ob  = qc;                          // alias (qc dead by then)

        convert_act<<<dim3(2048, 3), bt, 0, stream>>>(q, k, v, qc, kc, vc);
        transpose_w<<<dim3(16, 16, 4), bt, 0, stream>>>(Wq, Wk, Wv, Wo, Wt, Wot);
        gemm_fast<true, 128><<<dim3(24, 32), bt, 0, stream>>>(qc, kc, vc, Wt, bq, bk, bv, QKV, 3072);
        attn32_kernel<<<dim3(1024), bt, 0, stream>>>(QKV, QKV + 1024, QKV + 2048, Ob, 3072);
        gemm_fast<false, 64><<<dim3(16, 32), bt, 0, stream>>>(Ob, Ob, Ob, Wot, bo, bo, bo, d_out, 1024);
    } else {
        const size_t NE = (size_t)4096 * 1024;
        unsigned short* Qb = (unsigned short*)d_ws;
        unsigned short* Kb = Qb + NE;
        unsigned short* Vb = Kb + NE;
        unsigned short* Ob = Vb + NE;
        dim3 gg(8, 32);
        gemm_kernel<false, true><<<gg, bt, 0, stream>>>(q, Wq, bq, Qb);
        gemm_kernel<false, true><<<gg, bt, 0, stream>>>(k, Wk, bk, Kb);
        gemm_kernel<false, true><<<gg, bt, 0, stream>>>(v, Wv, bv, Vb);
        attn32_kernel<<<dim3(1024), bt, 0, stream>>>(Qb, Kb, Vb, Ob, 1024);
        gemm_kernel<true, false><<<gg, bt, 0, stream>>>(Ob, Wo, bo, d_out);
    }
}

// Round 6
// 232.911 us; speedup vs baseline: 1.1818x; 1.1818x over previous
//
#include <hip/hip_runtime.h>
#include <hip/hip_bf16.h>

typedef __attribute__((ext_vector_type(4))) float f32x4;
typedef __attribute__((ext_vector_type(16))) float f32x16;
typedef __attribute__((ext_vector_type(8))) short bf16x8;
typedef __attribute__((ext_vector_type(4))) unsigned short u16x4;
typedef __attribute__((ext_vector_type(8))) unsigned short u16x8;
typedef __attribute__((ext_vector_type(2))) unsigned int u32x2;

#define MFMA16(a, b, c) __builtin_amdgcn_mfma_f32_16x16x32_bf16((a), (b), (c), 0, 0, 0)
#define MFMA32(a, b, c) __builtin_amdgcn_mfma_f32_32x32x16_bf16((a), (b), (c), 0, 0, 0)

static __device__ __forceinline__ unsigned short f2bf(float f) {
    union { float f; unsigned int u; } v; v.f = f;
    unsigned int r = v.u + 0x7FFFu + ((v.u >> 16) & 1u);  // RNE
    return (unsigned short)(r >> 16);
}
// HW packed f32->bf16 (T12 recipe; src0 -> low half)
static __device__ __forceinline__ unsigned int pk2(float x, float y) {
    unsigned int r;
    asm("v_cvt_pk_bf16_f32 %0, %1, %2" : "=v"(r) : "v"(x), "v"(y));
    return r;
}
static __device__ __forceinline__ float bf2f(unsigned short u) {
    return __uint_as_float((unsigned int)u << 16);
}

static __device__ __forceinline__ void gload_lds16(const void* g, void* l) {
    __builtin_amdgcn_global_load_lds(
        (const __attribute__((address_space(1))) void*)g,
        (__attribute__((address_space(3))) void*)l, 16, 0, 0);
}

// ---------------------------------------------------------------------------
// prepass: fused activation convert (fp32->bf16) + weight transpose.
// blocks [0,6144): convert q/k/v (2048 blocks each, 8 elems/thread)
// blocks [6144,7168): transpose Wq/Wk/Wv/Wo 64x64 tiles -> bf16 [n][k]
// ---------------------------------------------------------------------------
__global__ __launch_bounds__(256) void prepass(
    const float* __restrict__ q, const float* __restrict__ k,
    const float* __restrict__ v, const float* __restrict__ Wq,
    const float* __restrict__ Wk, const float* __restrict__ Wv,
    const float* __restrict__ Wo, unsigned short* __restrict__ qc,
    unsigned short* __restrict__ kc, unsigned short* __restrict__ vc,
    unsigned short* __restrict__ Wt, unsigned short* __restrict__ Wot) {
    __shared__ unsigned short T[64][65];
    const int id = blockIdx.x, t = threadIdx.x;
    if (id < 6144) {
        const int z = id >> 11;  // /2048
        const float* src = z == 0 ? q : (z == 1 ? k : v);
        unsigned short* dst = z == 0 ? qc : (z == 1 ? kc : vc);
        size_t off = ((size_t)(id & 2047) * 256 + t) * 8;
        f32x4 a = *(const f32x4*)&src[off];
        f32x4 b = *(const f32x4*)&src[off + 4];
        union { unsigned int u[4]; u16x8 v; } o;
        o.u[0] = pk2(a[0], a[1]); o.u[1] = pk2(a[2], a[3]);
        o.u[2] = pk2(b[0], b[1]); o.u[3] = pk2(b[2], b[3]);
        *(u16x8*)&dst[off] = o.v;
    } else {
        int r = id - 6144;           // 0..1023
        const int z = r >> 8; r &= 255;
        const float* W = z == 0 ? Wq : (z == 1 ? Wk : (z == 2 ? Wv : Wo));
        unsigned short* Wd = z < 3 ? (Wt + (size_t)z * 1024 * 1024) : Wot;
        const int k0 = (r >> 4) * 64, n0 = (r & 15) * 64;
        const int rl = t >> 4, c4 = (t & 15) * 4;
#pragma unroll
        for (int i = 0; i < 4; ++i) {
            f32x4 vv = *(const f32x4*)&W[(size_t)(k0 + rl + 16 * i) * 1024 + n0 + c4];
#pragma unroll
            for (int j = 0; j < 4; ++j) T[rl + 16 * i][c4 + j] = f2bf(vv[j]);
        }
        __syncthreads();
#pragma unroll
        for (int i = 0; i < 4; ++i) {
            u16x4 o;
#pragma unroll
            for (int j = 0; j < 4; ++j) o[j] = T[c4 + j][rl + 16 * i];
            *(u16x4*)&Wd[(size_t)(n0 + rl + 16 * i) * 1024 + k0 + c4] = o;
        }
    }
}

// ---------------------------------------------------------------------------
// gemm_fast: 2-phase double-buffered m97 structure; BN=128 fixed, BM in
// {128,64}. 4 waves (2x2); wave computes (BM/2) x 64 via (BM/32)x4 16x16
// frags. global_load_lds x16, linear LDS, ds_read_b128, ONE barrier/K-step.
// ---------------------------------------------------------------------------
template <bool OUT_BF16, int BM>
__global__ __launch_bounds__(256, 2) void gemm_fast(
    const unsigned short* __restrict__ A0, const unsigned short* __restrict__ A1,
    const unsigned short* __restrict__ A2, const unsigned short* __restrict__ Wt,
    const float* __restrict__ b0, const float* __restrict__ b1,
    const float* __restrict__ b2, void* __restrict__ Outv, int ldo) {
    constexpr int MF = BM / 32;  // m-frags per wave
    __shared__ __align__(16) unsigned short As[2][BM * 32];
    __shared__ __align__(16) unsigned short Bs[2][128 * 32];

    const int t = threadIdx.x;
    const int w = t >> 6, lane = t & 63;
    const int wr = w >> 1, wc = w & 1;
    const int g = lane >> 4, r15 = lane & 15;
    const int bm = blockIdx.y * BM;
    const int bn = blockIdx.x * 128;
    const int msel = bn >> 10;
    const unsigned short* A = msel == 0 ? A0 : (msel == 1 ? A1 : A2);
    const float* bias = msel == 0 ? b0 : (msel == 1 ? b1 : b2);
    const int l4 = lane >> 2, c8 = (lane & 3) * 8;

    f32x4 acc[MF][4];
#pragma unroll
    for (int m = 0; m < MF; ++m)
#pragma unroll
        for (int n = 0; n < 4; ++n) acc[m][n] = (f32x4){0.f, 0.f, 0.f, 0.f};

#define G_STAGE(BUF, KT)                                                          \
    {                                                                             \
        gload_lds16(&A[(size_t)(bm + 16 * w + l4) * 1024 + (KT) + c8],            \
                    &As[BUF][w * 512]);                                           \
        if (BM == 128)                                                            \
            gload_lds16(&A[(size_t)(bm + 16 * (w + 4) + l4) * 1024 + (KT) + c8],  \
                        &As[BUF][((w + 4) * 512) % (BM * 32)]);                   \
        gload_lds16(&Wt[(size_t)(bn + 16 * w + l4) * 1024 + (KT) + c8],           \
                    &Bs[BUF][w * 512]);                                           \
        gload_lds16(&Wt[(size_t)(bn + 16 * (w + 4) + l4) * 1024 + (KT) + c8],     \
                    &Bs[BUF][(w + 4) * 512]);                                     \
    }

    G_STAGE(0, 0);
    __syncthreads();

    int cur = 0;
    for (int kt = 0; kt < 1024; kt += 32) {
        if (kt < 992) G_STAGE(cur ^ 1, kt + 32);
        bf16x8 af[MF], bfr[4];
#pragma unroll
        for (int m = 0; m < MF; ++m)
            af[m] = *(const bf16x8*)&As[cur][(wr * (BM / 2) + m * 16 + r15) * 32 + g * 8];
#pragma unroll
        for (int n = 0; n < 4; ++n)
            bfr[n] = *(const bf16x8*)&Bs[cur][(wc * 64 + n * 16 + r15) * 32 + g * 8];
        __builtin_amdgcn_s_setprio(1);
#pragma unroll
        for (int m = 0; m < MF; ++m)
#pragma unroll
            for (int n = 0; n < 4; ++n)
                acc[m][n] = MFMA16(af[m], bfr[n], acc[m][n]);
        __builtin_amdgcn_s_setprio(0);
        __syncthreads();
        cur ^= 1;
    }
#undef G_STAGE

    float* Of = (float*)Outv;
    unsigned short* Ob = (unsigned short*)Outv;
#pragma unroll
    for (int n = 0; n < 4; ++n) {
        int col = bn + wc * 64 + n * 16 + r15;
        float bv = bias[col & 1023];
#pragma unroll
        for (int m = 0; m < MF; ++m) {
#pragma unroll
            for (int r = 0; r < 4; ++r) {
                int row = bm + wr * (BM / 2) + m * 16 + g * 4 + r;
                float val = acc[m][n][r] + bv;
                if (OUT_BF16)
                    Ob[(size_t)row * ldo + col] = f2bf(val);
                else
                    Of[(size_t)row * ldo + col] = val;
            }
        }
    }
}

// ---------------------------------------------------------------------------
// attn32: swapped-operand 32x32 flash attention, BLOCK-LEVEL KV split.
// Each block = round-4 structure exactly (4 waves x 32 q = 128 q, single
// ping-pong double buffer, 1 barrier/tile) but covers only 512 keys
// (half = blockIdx parity). Writes self-normalized partial O (bf16) and
// (m,l) per (row,head); attn_merge does the LSE combine.
// Grid 1024 -> 4 blocks/CU (LDS 4x40KB = 160KB exact).
// ---------------------------------------------------------------------------
__global__ __launch_bounds__(256, 4) void attn32_kernel(
    const unsigned short* __restrict__ Q, const unsigned short* __restrict__ K,
    const unsigned short* __restrict__ V, unsigned short* __restrict__ Opart,
    float* __restrict__ ML, int ld) {
    __shared__ __align__(16) unsigned short Kls[2][64 * 80];
    __shared__ __align__(16) unsigned short Vls[2][64 * 80];

    const int t = threadIdx.x;
    const int w = t >> 6, lane = t & 63;
    const int q5 = lane & 31, hi = lane >> 5;

    // XCD swizzle (1024 blocks, bijective). 16 consecutive sid per (b,h).
    const int id = blockIdx.x;
    const int sid = (id & 7) * 128 + (id >> 3);
    const int bh = sid >> 4, sub = sid & 15;
    const int qb = sub >> 1, half = sub & 1;
    const int b = bh >> 4, h = bh & 15;
    const int brow = b * 1024;
    const int q0 = qb * 128;
    const int kv0 = half * 512;

    const float c2 = 0.18033688f;  // (1/8) * log2(e)

    const unsigned short* Qrow = Q + (size_t)(brow + q0 + w * 32 + q5) * ld + h * 64;
    bf16x8 qreg[8];
#pragma unroll
    for (int j = 0; j < 8; ++j) qreg[j] = *(const bf16x8*)&Qrow[8 * j];
    bf16x8 qsel[4];
#pragma unroll
    for (int kk = 0; kk < 4; ++kk) qsel[kk] = hi ? qreg[2 * kk + 1] : qreg[2 * kk];

    // staging roles: K by (row, 16B slot); V by (key-pair, d-chunk of 8)
    const int krow = t >> 2, kpart = t & 3;
    const int vp = t & 31, vdc = t >> 5;
    const unsigned short* Kg = K + h * 64;
    const unsigned short* Vg = V + h * 64;

    u16x8 kr0, kr1, vr0, vr1;
#define STG_LOAD(KT)                                                            \
    {                                                                           \
        size_t kro = (size_t)(brow + (KT) + krow) * ld;                         \
        kr0 = *(const u16x8*)&Kg[kro + kpart * 8];                              \
        kr1 = *(const u16x8*)&Kg[kro + kpart * 8 + 32];                         \
        size_t vro = (size_t)(brow + (KT) + 2 * vp) * ld;                       \
        vr0 = *(const u16x8*)&Vg[vro + vdc * 8];                                \
        vr1 = *(const u16x8*)&Vg[vro + ld + vdc * 8];                           \
    }
#define STG_WRITE(BUF)                                                          \
    {                                                                           \
        char* kb_ = (char*)Kls[BUF];                                            \
        int tg_ = (krow & 7) << 4;                                              \
        *(u16x8*)(kb_ + krow * 160 + ((kpart * 16) ^ tg_)) = kr0;               \
        *(u16x8*)(kb_ + krow * 160 + (((kpart + 4) * 16) ^ tg_)) = kr1;         \
        char* vb_ = (char*)Vls[BUF];                                            \
        _Pragma("unroll") for (int j_ = 0; j_ < 8; ++j_) {                      \
            int d_ = vdc * 8 + j_;                                              \
            unsigned int pk_ = (unsigned int)(unsigned short)vr0[j_] |          \
                               ((unsigned int)(unsigned short)vr1[j_] << 16);   \
            *(unsigned int*)(vb_ + d_ * 160 + ((vp * 4) ^ ((d_ & 7) << 4)))     \
                = pk_;                                                          \
        }                                                                       \
    }

    f32x16 acc0 = {}, acc1 = {};
    float mrun = -1e30f, lrun = 0.f;

    STG_LOAD(kv0);
    STG_WRITE(0);
    __syncthreads();

    int cur = 0;
    for (int tile = 0; tile < 8; ++tile) {
        const bool more = tile < 7;
        if (more) STG_LOAD(kv0 + tile * 64 + 64);

        // ---- QK^T
        char* kb = (char*)Kls[cur];
        f32x16 st0 = {}, st1 = {};
        {
            const int tg0 = (q5 & 7) << 4;
            char* kp0 = kb + q5 * 160;
            char* kp1 = kb + (q5 + 32) * 160;
            __builtin_amdgcn_s_setprio(1);
#pragma unroll
            for (int kk = 0; kk < 4; ++kk) {
                int so = ((2 * kk + hi) * 16) ^ tg0;
                bf16x8 kf0 = *(const bf16x8*)(kp0 + so);
                bf16x8 kf1 = *(const bf16x8*)(kp1 + so);
                st0 = MFMA32(kf0, qsel[kk], st0);
                st1 = MFMA32(kf1, qsel[kk], st1);
            }
            __builtin_amdgcn_s_setprio(0);
        }

        // ---- online softmax with defer-max (T13)
        float mloc = fmaxf(st0[0], st0[1]);
#pragma unroll
        for (int r = 2; r < 16; ++r) mloc = fmaxf(mloc, st0[r]);
#pragma unroll
        for (int r = 0; r < 16; ++r) mloc = fmaxf(mloc, st1[r]);
        mloc = fmaxf(mloc, __shfl_xor(mloc, 32));
        if (!__all(mloc - mrun <= 64.f)) {
            float mnew = fmaxf(mrun, mloc);
            float sf = exp2f((mrun - mnew) * c2);
            mrun = mnew;
            lrun *= sf;
#pragma unroll
            for (int r = 0; r < 16; ++r) { acc0[r] *= sf; acc1[r] *= sf; }
        }
        float mneg = -mrun * c2;
        float rs = 0.f;
#pragma unroll
        for (int r = 0; r < 16; ++r) {
            st0[r] = exp2f(fmaf(st0[r], c2, mneg));
            rs += st0[r];
        }
#pragma unroll
        for (int r = 0; r < 16; ++r) {
            st1[r] = exp2f(fmaf(st1[r], c2, mneg));
            rs += st1[r];
        }
        rs += __shfl_xor(rs, 32);
        lrun += rs;

        // ---- P^T pack (cvt_pk) + PV (O^T += V^T * P^T)
        char* vb = (char*)Vls[cur];
        const int tgv = (q5 & 7) << 4;
        char* vp0 = vb + q5 * 160;
        char* vp1 = vb + (q5 + 32) * 160;
        __builtin_amdgcn_s_setprio(1);
#define PV_HALF(ST, CT)                                                         \
    _Pragma("unroll") for (int ks = 0; ks < 2; ++ks) {                          \
        unsigned int a0 = pk2(ST[8 * ks + 0], ST[8 * ks + 1]);                  \
        unsigned int a1 = pk2(ST[8 * ks + 2], ST[8 * ks + 3]);                  \
        unsigned int a2 = pk2(ST[8 * ks + 4], ST[8 * ks + 5]);                  \
        unsigned int a3 = pk2(ST[8 * ks + 6], ST[8 * ks + 7]);                  \
        unsigned int x0 = __shfl_xor(a0, 32), x1 = __shfl_xor(a1, 32);          \
        unsigned int x2 = __shfl_xor(a2, 32), x3 = __shfl_xor(a3, 32);          \
        union { unsigned int u[4]; bf16x8 v; } pfu;                             \
        pfu.u[0] = hi ? x2 : a0;                                                \
        pfu.u[1] = hi ? x3 : a1;                                                \
        pfu.u[2] = hi ? a2 : x0;                                                \
        pfu.u[3] = hi ? a3 : x1;                                                \
        int co = ((32 * (2 * (CT) + ks) + 16 * hi)) ^ tgv;                      \
        bf16x8 vf0 = *(const bf16x8*)(vp0 + co);                                \
        bf16x8 vf1 = *(const bf16x8*)(vp1 + co);                                \
        acc0 = MFMA32(vf0, pfu.v, acc0);                                        \
        acc1 = MFMA32(vf1, pfu.v, acc1);                                        \
    }
        PV_HALF(st0, 0);
        PV_HALF(st1, 1);
        __builtin_amdgcn_s_setprio(0);

        if (more) STG_WRITE(cur ^ 1);
        __syncthreads();
        cur ^= 1;
    }

    // ---- epilogue: self-normalized partial + (m,l)
    const int grow = brow + q0 + w * 32 + q5;
    const float inv = 1.0f / lrun;
    unsigned short* Orow =
        Opart + (size_t)half * 4194304 + (size_t)grow * 1024 + h * 64;
#pragma unroll
    for (int k = 0; k < 4; ++k) {
        int d0 = 8 * k + 4 * hi;
        u32x2 pa, pb;
        pa[0] = pk2(acc0[4 * k + 0] * inv, acc0[4 * k + 1] * inv);
        pa[1] = pk2(acc0[4 * k + 2] * inv, acc0[4 * k + 3] * inv);
        *(u32x2*)&Orow[d0] = pa;
        pb[0] = pk2(acc1[4 * k + 0] * inv, acc1[4 * k + 1] * inv);
        pb[1] = pk2(acc1[4 * k + 2] * inv, acc1[4 * k + 3] * inv);
        *(u32x2*)&Orow[32 + d0] = pb;
    }
    if (hi == 0)
        ((float2*)ML)[half * 65536 + grow * 16 + h] = make_float2(mrun, lrun);
#undef STG_LOAD
#undef STG_WRITE
#undef PV_HALF
}

// ---------------------------------------------------------------------------
// attn_merge: LSE-combine the two KV-half partials. 8 threads per (row,head),
// each handles 8 of 64 d. 2048 blocks x 256 threads.
// ---------------------------------------------------------------------------
__global__ __launch_bounds__(256) void attn_merge(
    const unsigned short* __restrict__ Opart, const float* __restrict__ ML,
    unsigned short* __restrict__ Omg) {
    const float c2 = 0.18033688f;
    const int gid = blockIdx.x * 256 + threadIdx.x;
    const int pair = gid >> 3;   // row*16 + h
    const int dp = gid & 7;
    const int row = pair >> 4, h = pair & 15;
    const float2 ml0 = ((const float2*)ML)[pair];
    const float2 ml1 = ((const float2*)ML)[65536 + pair];
    float mn = fmaxf(ml0.x, ml1.x);
    float w0 = ml0.y * exp2f((ml0.x - mn) * c2);
    float w1 = ml1.y * exp2f((ml1.x - mn) * c2);
    float inv = 1.0f / (w0 + w1);
    w0 *= inv; w1 *= inv;
    size_t off = (size_t)row * 1024 + h * 64 + dp * 8;
    u16x8 a = *(const u16x8*)&Opart[off];
    u16x8 b = *(const u16x8*)&Opart[4194304 + off];
    union { unsigned int u[4]; u16x8 v; } o;
#pragma unroll
    for (int j = 0; j < 4; ++j)
        o.u[j] = pk2(bf2f(a[2 * j]) * w0 + bf2f(b[2 * j]) * w1,
                     bf2f(a[2 * j + 1]) * w0 + bf2f(b[2 * j + 1]) * w1);
    *(u16x8*)&Omg[off] = o.v;
}

extern "C" void kernel_launch(void* const* d_in, const int* in_sizes, int n_in,
                              void* d_out, int out_size, void* d_ws, size_t ws_size,
                              hipStream_t stream) {
    const float* q  = (const float*)d_in[0];
    const float* k  = (const float*)d_in[1];
    const float* v  = (const float*)d_in[2];
    const float* Wq = (const float*)d_in[3];
    const float* bq = (const float*)d_in[4];
    const float* Wk = (const float*)d_in[5];
    const float* bk = (const float*)d_in[6];
    const float* Wv = (const float*)d_in[7];
    const float* bv = (const float*)d_in[8];
    const float* Wo = (const float*)d_in[9];
    const float* bo = (const float*)d_in[10];

    const size_t M1 = (size_t)1024 * 1024;
    // ws layout (56 MB, harness-verified >= this since round 2):
    unsigned short* qc  = (unsigned short*)d_ws;   // 4M elems (8 MB)
    unsigned short* kc  = qc + 4 * M1;             // 4M
    unsigned short* vc  = kc + 4 * M1;             // 4M
    unsigned short* Wt  = vc + 4 * M1;             // 3M  [3072][1024]
    unsigned short* Wot = Wt + 3 * M1;             // 1M
    unsigned short* QKV = Wot + M1;                // 12M [4096][3072]
    // aliases after their producers are dead:
    unsigned short* Opart = qc;                    // 8M elems (qc+kc, dead post-QKV)
    float* ML = (float*)vc;                        // 1 MB of vc (dead post-QKV)
    unsigned short* Omg = QKV;                     // 4M elems (QKV dead post-attn)

    dim3 bt(256, 1, 1);
    prepass<<<dim3(7168), bt, 0, stream>>>(q, k, v, Wq, Wk, Wv, Wo,
                                           qc, kc, vc, Wt, Wot);
    gemm_fast<true, 128><<<dim3(24, 32), bt, 0, stream>>>(
        qc, kc, vc, Wt, bq, bk, bv, QKV, 3072);
    attn32_kernel<<<dim3(1024), bt, 0, stream>>>(
        QKV, QKV + 1024, QKV + 2048, Opart, ML, 3072);
    attn_merge<<<dim3(2048), bt, 0, stream>>>(Opart, ML, Omg);
    gemm_fast<false, 64><<<dim3(8, 64), bt, 0, stream>>>(
        Omg, Omg, Omg, Wot, bo, bo, bo, d_out, 1024);
}

// Round 7
// 211.884 us; speedup vs baseline: 1.2991x; 1.0992x over previous
//
#include <hip/hip_runtime.h>
#include <hip/hip_bf16.h>

typedef __attribute__((ext_vector_type(4))) float f32x4;
typedef __attribute__((ext_vector_type(16))) float f32x16;
typedef __attribute__((ext_vector_type(8))) short bf16x8;
typedef __attribute__((ext_vector_type(4))) unsigned short u16x4;
typedef __attribute__((ext_vector_type(8))) unsigned short u16x8;
typedef __attribute__((ext_vector_type(2))) unsigned int u32x2;

#define MFMA16(a, b, c) __builtin_amdgcn_mfma_f32_16x16x32_bf16((a), (b), (c), 0, 0, 0)
#define MFMA32(a, b, c) __builtin_amdgcn_mfma_f32_32x32x16_bf16((a), (b), (c), 0, 0, 0)

static __device__ __forceinline__ unsigned short f2bf(float f) {
    union { float f; unsigned int u; } v; v.f = f;
    unsigned int r = v.u + 0x7FFFu + ((v.u >> 16) & 1u);  // RNE
    return (unsigned short)(r >> 16);
}
// HW packed f32->bf16 (T12 recipe; src0 -> low half)
static __device__ __forceinline__ unsigned int pk2(float x, float y) {
    unsigned int r;
    asm("v_cvt_pk_bf16_f32 %0, %1, %2" : "=v"(r) : "v"(x), "v"(y));
    return r;
}

static __device__ __forceinline__ void gload_lds16(const void* g, void* l) {
    __builtin_amdgcn_global_load_lds(
        (const __attribute__((address_space(1))) void*)g,
        (__attribute__((address_space(3))) void*)l, 16, 0, 0);
}

// ---------------------------------------------------------------------------
// prepass: fused activation convert (fp32->bf16) + weight transpose.
// blocks [0,6144): convert q/k/v (2048 blocks each, 8 elems/thread)
// blocks [6144,7168): transpose Wq/Wk/Wv/Wo 64x64 tiles -> bf16 [n][k]
// ---------------------------------------------------------------------------
__global__ __launch_bounds__(256) void prepass(
    const float* __restrict__ q, const float* __restrict__ k,
    const float* __restrict__ v, const float* __restrict__ Wq,
    const float* __restrict__ Wk, const float* __restrict__ Wv,
    const float* __restrict__ Wo, unsigned short* __restrict__ qc,
    unsigned short* __restrict__ kc, unsigned short* __restrict__ vc,
    unsigned short* __restrict__ Wt, unsigned short* __restrict__ Wot) {
    __shared__ unsigned short T[64][65];
    const int id = blockIdx.x, t = threadIdx.x;
    if (id < 6144) {
        const int z = id >> 11;  // /2048
        const float* src = z == 0 ? q : (z == 1 ? k : v);
        unsigned short* dst = z == 0 ? qc : (z == 1 ? kc : vc);
        size_t off = ((size_t)(id & 2047) * 256 + t) * 8;
        f32x4 a = *(const f32x4*)&src[off];
        f32x4 b = *(const f32x4*)&src[off + 4];
        union { unsigned int u[4]; u16x8 v; } o;
        o.u[0] = pk2(a[0], a[1]); o.u[1] = pk2(a[2], a[3]);
        o.u[2] = pk2(b[0], b[1]); o.u[3] = pk2(b[2], b[3]);
        *(u16x8*)&dst[off] = o.v;
    } else {
        int r = id - 6144;           // 0..1023
        const int z = r >> 8; r &= 255;
        const float* W = z == 0 ? Wq : (z == 1 ? Wk : (z == 2 ? Wv : Wo));
        unsigned short* Wd = z < 3 ? (Wt + (size_t)z * 1024 * 1024) : Wot;
        const int k0 = (r >> 4) * 64, n0 = (r & 15) * 64;
        const int rl = t >> 4, c4 = (t & 15) * 4;
#pragma unroll
        for (int i = 0; i < 4; ++i) {
            f32x4 vv = *(const f32x4*)&W[(size_t)(k0 + rl + 16 * i) * 1024 + n0 + c4];
#pragma unroll
            for (int j = 0; j < 4; ++j) T[rl + 16 * i][c4 + j] = f2bf(vv[j]);
        }
        __syncthreads();
#pragma unroll
        for (int i = 0; i < 4; ++i) {
            u16x4 o;
#pragma unroll
            for (int j = 0; j < 4; ++j) o[j] = T[c4 + j][rl + 16 * i];
            *(u16x4*)&Wd[(size_t)(n0 + rl + 16 * i) * 1024 + k0 + c4] = o;
        }
    }
}

// ---------------------------------------------------------------------------
// gemm_fast: 2-phase double-buffered m97 structure, XCD-chunked 1-D grid.
// BMxBN tile (128x128 QKV / 64x64 out-proj), 4 waves (2x2), BK=32,
// global_load_lds x16, linear LDS, ds_read_b128, ONE barrier/K-step.
// SWZ=0: 32 M-tiles x 24 N-tiles (768 blocks) -> 16 chunks of 8Mx6N,
//        2 chunks per XCD (A 2MB + B 1.5MB per chunk: L2-resident).
// SWZ=1: 64 M-tiles x 16 N-tiles (1024 blocks) -> XCD x owns M-tile band
//        [8x, 8x+8) x all N (A 1MB + B 2MB: L2-resident).
// ---------------------------------------------------------------------------
template <bool OUT_BF16, int BM, int BN, int SWZ, int MINW>
__global__ __launch_bounds__(256, MINW) void gemm_fast(
    const unsigned short* __restrict__ A0, const unsigned short* __restrict__ A1,
    const unsigned short* __restrict__ A2, const unsigned short* __restrict__ Wt,
    const float* __restrict__ b0, const float* __restrict__ b1,
    const float* __restrict__ b2, void* __restrict__ Outv, int ldo) {
    constexpr int MF = BM / 32;  // m-frags per wave
    constexpr int NF = BN / 32;  // n-frags per wave
    __shared__ __align__(16) unsigned short As[2][BM * 32];
    __shared__ __align__(16) unsigned short Bs[2][BN * 32];

    const int t = threadIdx.x;
    const int w = t >> 6, lane = t & 63;  // w in [0,4)
    const int wr = w >> 1, wc = w & 1;
    const int g = lane >> 4, r15 = lane & 15;

    // XCD-chunked block id -> (bm, bn)
    const int id = blockIdx.x;
    int bm, bn;
    if (SWZ == 0) {
        const int xcd = id & 7, local = id >> 3;          // local in [0,96)
        const int half = local >= 48 ? 1 : 0;
        const int ww = local - half * 48;                 // [0,48)
        const int gg = xcd * 2 + half;                    // chunk [0,16)
        bm = ((gg >> 2) * 8 + (ww & 7)) * BM;             // mt in [0,32)
        bn = ((gg & 3) * 6 + (ww >> 3)) * BN;             // nt in [0,24)
    } else {
        const int xcd = id & 7, local = id >> 3;          // local in [0,128)
        bm = (xcd * 8 + (local & 7)) * BM;                // mt in [0,64)
        bn = (local >> 3) * BN;                           // nt in [0,16)
    }
    const int msel = bn >> 10;
    const unsigned short* A = msel == 0 ? A0 : (msel == 1 ? A1 : A2);
    const float* bias = msel == 0 ? b0 : (msel == 1 ? b1 : b2);
    const int l4 = lane >> 2, c8 = (lane & 3) * 8;

    f32x4 acc[MF][NF];
#pragma unroll
    for (int m = 0; m < MF; ++m)
#pragma unroll
        for (int n = 0; n < NF; ++n) acc[m][n] = (f32x4){0.f, 0.f, 0.f, 0.f};

#define G_STAGE(BUF, KT)                                                          \
    {                                                                             \
        gload_lds16(&A[(size_t)(bm + 16 * w + l4) * 1024 + (KT) + c8],            \
                    &As[BUF][w * 512]);                                           \
        if (BM == 128)                                                            \
            gload_lds16(&A[(size_t)(bm + 16 * (w + 4) + l4) * 1024 + (KT) + c8],  \
                        &As[BUF][(w + 4) * 512]);                                 \
        gload_lds16(&Wt[(size_t)(bn + 16 * w + l4) * 1024 + (KT) + c8],           \
                    &Bs[BUF][w * 512]);                                           \
        if (BN == 128)                                                            \
            gload_lds16(&Wt[(size_t)(bn + 16 * (w + 4) + l4) * 1024 + (KT) + c8], \
                        &Bs[BUF][(w + 4) * 512]);                                 \
    }

    G_STAGE(0, 0);
    __syncthreads();

    int cur = 0;
    for (int kt = 0; kt < 1024; kt += 32) {
        if (kt < 992) G_STAGE(cur ^ 1, kt + 32);
        bf16x8 af[MF], bfr[NF];
#pragma unroll
        for (int m = 0; m < MF; ++m)
            af[m] = *(const bf16x8*)&As[cur][(wr * (BM / 2) + m * 16 + r15) * 32 + g * 8];
#pragma unroll
        for (int n = 0; n < NF; ++n)
            bfr[n] = *(const bf16x8*)&Bs[cur][(wc * (BN / 2) + n * 16 + r15) * 32 + g * 8];
        __builtin_amdgcn_s_setprio(1);
#pragma unroll
        for (int m = 0; m < MF; ++m)
#pragma unroll
            for (int n = 0; n < NF; ++n)
                acc[m][n] = MFMA16(af[m], bfr[n], acc[m][n]);
        __builtin_amdgcn_s_setprio(0);
        __syncthreads();
        cur ^= 1;
    }
#undef G_STAGE

    float* Of = (float*)Outv;
    unsigned short* Ob = (unsigned short*)Outv;
#pragma unroll
    for (int n = 0; n < NF; ++n) {
        int col = bn + wc * (BN / 2) + n * 16 + r15;
        float bv = bias[col & 1023];
#pragma unroll
        for (int m = 0; m < MF; ++m) {
#pragma unroll
            for (int r = 0; r < 4; ++r) {
                int row = bm + wr * (BM / 2) + m * 16 + g * 4 + r;
                float val = acc[m][n][r] + bv;
                if (OUT_BF16)
                    Ob[(size_t)row * ldo + col] = f2bf(val);
                else
                    Of[(size_t)row * ldo + col] = val;
            }
        }
    }
}

// ---------------------------------------------------------------------------
// attn32: swapped-operand 32x32 flash attention (round-4 proven version).
// 4 waves x 32 q-rows = 128 q/block; KVBLK=64, double-buffered swizzled LDS.
// QK^T: mfma(A=K, B=Q) -> S^T (lane owns q=lane&31, keys in regs).
// PV:   mfma(A=V^T, B=P^T) -> O^T (q stays on lane; rescale lane-local).
// cvt_pk asm pack, defer-max (THR=64 raw = 8 exp-units), b32 V staging,
// s_setprio around MFMA clusters. Grid 512, (256,2) -> no VGPR spills.
// ---------------------------------------------------------------------------
__global__ __launch_bounds__(256, 2) void attn32_kernel(
    const unsigned short* __restrict__ Q, const unsigned short* __restrict__ K,
    const unsigned short* __restrict__ V, unsigned short* __restrict__ O, int ld) {
    __shared__ __align__(16) unsigned short Kls[2][64 * 80];
    __shared__ __align__(16) unsigned short Vls[2][64 * 80];

    const int t = threadIdx.x;
    const int w = t >> 6, lane = t & 63;
    const int q5 = lane & 31, hi = lane >> 5;

    const int id = blockIdx.x;
    const int sid = (id & 7) * 64 + (id >> 3);
    const int bh = sid >> 3, qb = sid & 7;
    const int b = bh >> 4, h = bh & 15;
    const int brow = b * 1024;
    const int q0 = qb * 128;

    const float c2 = 0.18033688f;  // (1/8) * log2(e)

    const unsigned short* Qrow = Q + (size_t)(brow + q0 + w * 32 + q5) * ld + h * 64;
    bf16x8 qreg[8];
#pragma unroll
    for (int j = 0; j < 8; ++j) qreg[j] = *(const bf16x8*)&Qrow[8 * j];
    bf16x8 qsel[4];
#pragma unroll
    for (int kk = 0; kk < 4; ++kk) qsel[kk] = hi ? qreg[2 * kk + 1] : qreg[2 * kk];

    // staging roles: K by (row, 16B slot); V by (key-pair, d-chunk of 8)
    const int krow = t >> 2, kpart = t & 3;
    const int vp = t & 31, vdc = t >> 5;
    const unsigned short* Kg = K + h * 64;
    const unsigned short* Vg = V + h * 64;

    u16x8 kr0, kr1, vr0, vr1;
#define STG_LOAD(KT)                                                            \
    {                                                                           \
        size_t kro = (size_t)(brow + (KT) + krow) * ld;                         \
        kr0 = *(const u16x8*)&Kg[kro + kpart * 8];                              \
        kr1 = *(const u16x8*)&Kg[kro + kpart * 8 + 32];                         \
        size_t vro = (size_t)(brow + (KT) + 2 * vp) * ld;                       \
        vr0 = *(const u16x8*)&Vg[vro + vdc * 8];                                \
        vr1 = *(const u16x8*)&Vg[vro + ld + vdc * 8];                           \
    }
#define STG_WRITE(BUF)                                                          \
    {                                                                           \
        char* kb_ = (char*)Kls[BUF];                                            \
        int tg_ = (krow & 7) << 4;                                              \
        *(u16x8*)(kb_ + krow * 160 + ((kpart * 16) ^ tg_)) = kr0;               \
        *(u16x8*)(kb_ + krow * 160 + (((kpart + 4) * 16) ^ tg_)) = kr1;         \
        char* vb_ = (char*)Vls[BUF];                                            \
        _Pragma("unroll") for (int j_ = 0; j_ < 8; ++j_) {                      \
            int d_ = vdc * 8 + j_;                                              \
            unsigned int pk_ = (unsigned int)(unsigned short)vr0[j_] |          \
                               ((unsigned int)(unsigned short)vr1[j_] << 16);   \
            *(unsigned int*)(vb_ + d_ * 160 + ((vp * 4) ^ ((d_ & 7) << 4)))     \
                = pk_;                                                          \
        }                                                                       \
    }

    f32x16 acc0 = {}, acc1 = {};
    float mrun = -1e30f, lrun = 0.f;

    STG_LOAD(0);
    STG_WRITE(0);
    __syncthreads();

    int cur = 0;
    for (int tile = 0; tile < 16; ++tile) {
        const bool more = tile < 15;
        if (more) STG_LOAD(tile * 64 + 64);

        // ---- QK^T
        char* kb = (char*)Kls[cur];
        f32x16 st0 = {}, st1 = {};
        {
            const int tg0 = (q5 & 7) << 4;
            char* kp0 = kb + q5 * 160;
            char* kp1 = kb + (q5 + 32) * 160;
            __builtin_amdgcn_s_setprio(1);
#pragma unroll
            for (int kk = 0; kk < 4; ++kk) {
                int so = ((2 * kk + hi) * 16) ^ tg0;
                bf16x8 kf0 = *(const bf16x8*)(kp0 + so);
                bf16x8 kf1 = *(const bf16x8*)(kp1 + so);
                st0 = MFMA32(kf0, qsel[kk], st0);
                st1 = MFMA32(kf1, qsel[kk], st1);
            }
            __builtin_amdgcn_s_setprio(0);
        }

        // ---- online softmax with defer-max (T13)
        float mloc = fmaxf(st0[0], st0[1]);
#pragma unroll
        for (int r = 2; r < 16; ++r) mloc = fmaxf(mloc, st0[r]);
#pragma unroll
        for (int r = 0; r < 16; ++r) mloc = fmaxf(mloc, st1[r]);
        mloc = fmaxf(mloc, __shfl_xor(mloc, 32));
        if (!__all(mloc - mrun <= 64.f)) {
            float mnew = fmaxf(mrun, mloc);
            float sf = exp2f((mrun - mnew) * c2);
            mrun = mnew;
            lrun *= sf;
#pragma unroll
            for (int r = 0; r < 16; ++r) { acc0[r] *= sf; acc1[r] *= sf; }
        }
        float mneg = -mrun * c2;
        float rs = 0.f;
#pragma unroll
        for (int r = 0; r < 16; ++r) {
            st0[r] = exp2f(fmaf(st0[r], c2, mneg));
            rs += st0[r];
        }
#pragma unroll
        for (int r = 0; r < 16; ++r) {
            st1[r] = exp2f(fmaf(st1[r], c2, mneg));
            rs += st1[r];
        }
        rs += __shfl_xor(rs, 32);
        lrun += rs;

        // ---- P^T pack (cvt_pk) + PV (O^T += V^T * P^T)
        char* vb = (char*)Vls[cur];
        const int tgv = (q5 & 7) << 4;
        char* vp0 = vb + q5 * 160;
        char* vp1 = vb + (q5 + 32) * 160;
        __builtin_amdgcn_s_setprio(1);
#define PV_HALF(ST, CT)                                                         \
    _Pragma("unroll") for (int ks = 0; ks < 2; ++ks) {                          \
        unsigned int a0 = pk2(ST[8 * ks + 0], ST[8 * ks + 1]);                  \
        unsigned int a1 = pk2(ST[8 * ks + 2], ST[8 * ks + 3]);                  \
        unsigned int a2 = pk2(ST[8 * ks + 4], ST[8 * ks + 5]);                  \
        unsigned int a3 = pk2(ST[8 * ks + 6], ST[8 * ks + 7]);                  \
        unsigned int x0 = __shfl_xor(a0, 32), x1 = __shfl_xor(a1, 32);          \
        unsigned int x2 = __shfl_xor(a2, 32), x3 = __shfl_xor(a3, 32);          \
        union { unsigned int u[4]; bf16x8 v; } pfu;                             \
        pfu.u[0] = hi ? x2 : a0;                                                \
        pfu.u[1] = hi ? x3 : a1;                                                \
        pfu.u[2] = hi ? a2 : x0;                                                \
        pfu.u[3] = hi ? a3 : x1;                                                \
        int co = ((32 * (2 * (CT) + ks) + 16 * hi)) ^ tgv;                      \
        bf16x8 vf0 = *(const bf16x8*)(vp0 + co);                                \
        bf16x8 vf1 = *(const bf16x8*)(vp1 + co);                                \
        acc0 = MFMA32(vf0, pfu.v, acc0);                                        \
        acc1 = MFMA32(vf1, pfu.v, acc1);                                        \
    }
        PV_HALF(st0, 0);
        PV_HALF(st1, 1);
        __builtin_amdgcn_s_setprio(0);

        if (more) STG_WRITE(cur ^ 1);
        __syncthreads();
        cur ^= 1;
    }

    // ---- epilogue
    const float inv = 1.0f / lrun;
    unsigned short* Orow = O + (size_t)(brow + q0 + w * 32 + q5) * 1024 + h * 64;
#pragma unroll
    for (int k = 0; k < 4; ++k) {
        int d0 = 8 * k + 4 * hi;
        u32x2 pa, pb;
        pa[0] = pk2(acc0[4 * k + 0] * inv, acc0[4 * k + 1] * inv);
        pa[1] = pk2(acc0[4 * k + 2] * inv, acc0[4 * k + 3] * inv);
        *(u32x2*)&Orow[d0] = pa;
        pb[0] = pk2(acc1[4 * k + 0] * inv, acc1[4 * k + 1] * inv);
        pb[1] = pk2(acc1[4 * k + 2] * inv, acc1[4 * k + 3] * inv);
        *(u32x2*)&Orow[32 + d0] = pb;
    }
#undef STG_LOAD
#undef STG_WRITE
#undef PV_HALF
}

extern "C" void kernel_launch(void* const* d_in, const int* in_sizes, int n_in,
                              void* d_out, int out_size, void* d_ws, size_t ws_size,
                              hipStream_t stream) {
    const float* q  = (const float*)d_in[0];
    const float* k  = (const float*)d_in[1];
    const float* v  = (const float*)d_in[2];
    const float* Wq = (const float*)d_in[3];
    const float* bq = (const float*)d_in[4];
    const float* Wk = (const float*)d_in[5];
    const float* bk = (const float*)d_in[6];
    const float* Wv = (const float*)d_in[7];
    const float* bv = (const float*)d_in[8];
    const float* Wo = (const float*)d_in[9];
    const float* bo = (const float*)d_in[10];

    const size_t M1 = (size_t)1024 * 1024;
    // ws layout (56 MB):
    unsigned short* qc  = (unsigned short*)d_ws;   // 4M elems (8 MB)
    unsigned short* kc  = qc + 4 * M1;             // 4M
    unsigned short* vc  = kc + 4 * M1;             // 4M
    unsigned short* Wt  = vc + 4 * M1;             // 3M  [3072][1024]
    unsigned short* Wot = Wt + 3 * M1;             // 1M
    unsigned short* QKV = Wot + M1;                // 12M [4096][3072]
    unsigned short* Ob  = qc;                      // alias (qc dead post-QKV)

    dim3 bt(256, 1, 1);
    prepass<<<dim3(7168), bt, 0, stream>>>(q, k, v, Wq, Wk, Wv, Wo,
                                           qc, kc, vc, Wt, Wot);
    gemm_fast<true, 128, 128, 0, 2><<<dim3(768), bt, 0, stream>>>(
        qc, kc, vc, Wt, bq, bk, bv, QKV, 3072);
    attn32_kernel<<<dim3(512), bt, 0, stream>>>(
        QKV, QKV + 1024, QKV + 2048, Ob, 3072);
    gemm_fast<false, 64, 64, 1, 4><<<dim3(1024), bt, 0, stream>>>(
        Ob, Ob, Ob, Wot, bo, bo, bo, d_out, 1024);
}